// Round 1
// baseline (390.180 us; speedup 1.0000x reference)
//
#include <hip/hip_runtime.h>

// Problem constants (from reference)
constexpr int N_NODES = 50000;
constexpr int N_EDGES = 800000;
constexpr int D = 64;          // D_IN == D_OUT == 64

// ---------------------------------------------------------------------------
// Kernel 1: scatter-add raw x[row] into sums[col], count edges per col.
// Exploits linearity: segment_sum(msgs[row]) == W_msg @ segment_sum(x[row]).
// One wave (64 lanes) per edge; lane = feature index.
// ---------------------------------------------------------------------------
__global__ __launch_bounds__(256) void sage_scatter(
    const float* __restrict__ x,
    const int* __restrict__ edge_index,   // [2, N_EDGES] flat; [0]=row(src), [1]=col(dst)
    float* __restrict__ sums,             // [N_NODES, D]
    float* __restrict__ counts)           // [N_NODES]
{
    int tid  = blockIdx.x * blockDim.x + threadIdx.x;
    int edge = tid >> 6;                  // 64 threads per edge
    int lane = tid & 63;
    if (edge >= N_EDGES) return;

    int row = edge_index[edge];               // source node
    int col = edge_index[N_EDGES + edge];     // destination node

    float v = x[row * D + lane];              // coalesced 256B per wave
    atomicAdd(&sums[col * D + lane], v);
    if (lane == 0) atomicAdd(&counts[col], 1.0f);
}

// ---------------------------------------------------------------------------
// Kernel 2: out[n] = W_self @ x[n] + b_self + [cnt>0] (W_msg @ (sum[n]/cnt) + b_msg)
// 256 threads = 4 nodes x 64 output dims. W matrices staged transposed in LDS
// with stride 65 (padding: write stride-65 ~2-way, read consecutive ~2-way —
// both free per m136). x/sum row elements broadcast across the wave via shfl.
// ---------------------------------------------------------------------------
constexpr int LDS_STRIDE = D + 1;  // 65

__global__ __launch_bounds__(256) void sage_finalize(
    const float* __restrict__ x,
    const float* __restrict__ W_msg,  const float* __restrict__ b_msg,
    const float* __restrict__ W_self, const float* __restrict__ b_self,
    const float* __restrict__ sums,   const float* __restrict__ counts,
    float* __restrict__ out)
{
    __shared__ float Wm_t[D * LDS_STRIDE];  // Wm_t[k*65 + o] = W_msg[o*D + k]
    __shared__ float Ws_t[D * LDS_STRIDE];

    int tid = threadIdx.x;
    // cooperative transpose-load: i = o*D + k
    for (int i = tid; i < D * D; i += 256) {
        int o = i >> 6;
        int k = i & 63;
        Wm_t[k * LDS_STRIDE + o] = W_msg[i];
        Ws_t[k * LDS_STRIDE + o] = W_self[i];
    }
    __syncthreads();

    int node = blockIdx.x * 4 + (tid >> 6);
    int o    = tid & 63;
    if (node >= N_NODES) return;

    float cnt = counts[node];
    float inv = (cnt > 0.0f) ? (1.0f / cnt) : 0.0f;

    // each lane loads one element of its node's x-row and mean-row
    float myx = x[node * D + o];
    float mys = sums[node * D + o] * inv;

    float acc = b_self[o] + ((cnt > 0.0f) ? b_msg[o] : 0.0f);

    #pragma unroll
    for (int k = 0; k < D; ++k) {
        float xk = __shfl(myx, k);       // broadcast x[node][k] across the wave
        float sk = __shfl(mys, k);       // broadcast mean[node][k]
        acc += Ws_t[k * LDS_STRIDE + o] * xk
             + Wm_t[k * LDS_STRIDE + o] * sk;
    }

    out[node * D + o] = acc;
}

// ---------------------------------------------------------------------------
extern "C" void kernel_launch(void* const* d_in, const int* in_sizes, int n_in,
                              void* d_out, int out_size, void* d_ws, size_t ws_size,
                              hipStream_t stream) {
    const float* x       = (const float*)d_in[0];
    const int*   edges   = (const int*)  d_in[1];
    const float* W_msg   = (const float*)d_in[2];
    const float* b_msg   = (const float*)d_in[3];
    const float* W_self  = (const float*)d_in[4];
    const float* b_self  = (const float*)d_in[5];
    float*       out     = (float*)d_out;

    float* sums   = (float*)d_ws;                 // N_NODES * D
    float* counts = sums + (size_t)N_NODES * D;   // N_NODES

    // zero the accumulators (ws is re-poisoned to 0xAA before every launch)
    hipMemsetAsync(d_ws, 0,
                   ((size_t)N_NODES * D + N_NODES) * sizeof(float), stream);

    // scatter: 64 threads/edge, 4 edges per 256-thread block
    int scatter_blocks = (N_EDGES * 64) / 256;    // 200000
    sage_scatter<<<scatter_blocks, 256, 0, stream>>>(x, edges, sums, counts);

    // finalize: 4 nodes per 256-thread block
    int fin_blocks = (N_NODES + 3) / 4;           // 12500
    sage_finalize<<<fin_blocks, 256, 0, stream>>>(
        x, W_msg, b_msg, W_self, b_self, sums, counts, out);
}

// Round 2
// 212.778 us; speedup vs baseline: 1.8337x; 1.8337x over previous
//
#include <hip/hip_runtime.h>

constexpr int N_NODES = 50000;
constexpr int N_EDGES = 800000;
constexpr int D = 64;

constexpr int SCAN_BLOCKS = (N_NODES + 255) / 256;   // 196

typedef __attribute__((ext_vector_type(8))) short short8;
typedef __attribute__((ext_vector_type(4))) float f32x4;

static __device__ inline unsigned short f2bf(float f) {
    unsigned u = __float_as_uint(f);
    // round-to-nearest-even bf16
    unsigned r = (u + 0x7FFFu + ((u >> 16) & 1u)) >> 16;
    return (unsigned short)r;
}
static __device__ inline unsigned pack2(float lo, float hi) {
    return (unsigned)f2bf(lo) | ((unsigned)f2bf(hi) << 16);
}

// ---------------------------------------------------------------------------
// 1) histogram of destination degrees
// ---------------------------------------------------------------------------
__global__ __launch_bounds__(256) void k_hist(
    const int* __restrict__ edge_index, unsigned* __restrict__ counts)
{
    int t = blockIdx.x * 256 + threadIdx.x;
    if (t < N_EDGES) {
        int col = edge_index[N_EDGES + t];
        atomicAdd(&counts[col], 1u);
    }
}

// ---------------------------------------------------------------------------
// 2) exclusive scan of counts -> row_ptr (3 kernels)
// ---------------------------------------------------------------------------
__global__ __launch_bounds__(256) void k_scan_a(
    const unsigned* __restrict__ counts,
    unsigned* __restrict__ row_ptr, unsigned* __restrict__ block_sums)
{
    __shared__ unsigned s[256];
    int t = threadIdx.x;
    int i = blockIdx.x * 256 + t;
    unsigned c = (i < N_NODES) ? counts[i] : 0u;
    s[t] = c;
    __syncthreads();
    for (int off = 1; off < 256; off <<= 1) {
        unsigned v = (t >= off) ? s[t - off] : 0u;
        __syncthreads();
        s[t] += v;
        __syncthreads();
    }
    if (i < N_NODES) row_ptr[i] = s[t] - c;          // exclusive, chunk-local
    if (t == 255) block_sums[blockIdx.x] = s[255];
}

__global__ __launch_bounds__(256) void k_scan_b(unsigned* __restrict__ block_sums)
{
    __shared__ unsigned s[256];
    int t = threadIdx.x;
    unsigned c = (t < SCAN_BLOCKS) ? block_sums[t] : 0u;
    s[t] = c;
    __syncthreads();
    for (int off = 1; off < 256; off <<= 1) {
        unsigned v = (t >= off) ? s[t - off] : 0u;
        __syncthreads();
        s[t] += v;
        __syncthreads();
    }
    if (t < SCAN_BLOCKS) block_sums[t] = s[t] - c;   // exclusive
}

__global__ __launch_bounds__(256) void k_scan_c(
    unsigned* __restrict__ row_ptr, const unsigned* __restrict__ block_sums,
    unsigned* __restrict__ cursor)
{
    int i = blockIdx.x * 256 + threadIdx.x;
    if (i < N_NODES) {
        unsigned v = row_ptr[i] + block_sums[blockIdx.x];
        row_ptr[i] = v;
        cursor[i] = v;
    }
    if (i == 0) row_ptr[N_NODES] = (unsigned)N_EDGES;
}

// ---------------------------------------------------------------------------
// 3) placement: edge sources bucketed by destination (CSR adjacency)
// ---------------------------------------------------------------------------
__global__ __launch_bounds__(256) void k_place(
    const int* __restrict__ edge_index,
    unsigned* __restrict__ cursor, unsigned* __restrict__ edge_src)
{
    int t = blockIdx.x * 256 + threadIdx.x;
    if (t < N_EDGES) {
        int r = edge_index[t];
        int c = edge_index[N_EDGES + t];
        unsigned p = atomicAdd(&cursor[c], 1u);
        edge_src[p] = (unsigned)r;
    }
}

// ---------------------------------------------------------------------------
// 4) gather-mean: one wave per node, lane = feature. mean written to d_out.
// ---------------------------------------------------------------------------
__global__ __launch_bounds__(256) void k_gather(
    const float* __restrict__ x,
    const unsigned* __restrict__ row_ptr,
    const unsigned* __restrict__ edge_src,
    float* __restrict__ mean_out)
{
    int node = (int)((blockIdx.x * 256 + threadIdx.x) >> 6);
    int lane = threadIdx.x & 63;
    if (node >= N_NODES) return;

    unsigned start = row_ptr[node], end = row_ptr[node + 1];
    float a0 = 0.f, a1 = 0.f, a2 = 0.f, a3 = 0.f;

    for (unsigned base = start; base < end; base += 64u) {
        int m = (int)min(64u, end - base);
        int id = (lane < m) ? (int)edge_src[base + lane] : 0;
        int j = 0;
        for (; j + 4 <= m; j += 4) {
            int s0 = __shfl(id, j);
            int s1 = __shfl(id, j + 1);
            int s2 = __shfl(id, j + 2);
            int s3 = __shfl(id, j + 3);
            a0 += x[s0 * D + lane];
            a1 += x[s1 * D + lane];
            a2 += x[s2 * D + lane];
            a3 += x[s3 * D + lane];
        }
        for (; j < m; ++j) {
            int s = __shfl(id, j);
            a0 += x[s * D + lane];
        }
    }
    unsigned deg = end - start;
    float sum = (a0 + a1) + (a2 + a3);
    mean_out[node * D + lane] = deg ? sum / (float)deg : 0.0f;
}

// ---------------------------------------------------------------------------
// 5) GEMM epilogue: out = [x|mean]_bf16 @ [W_self;W_msg]_bf16^T + biases.
//    M=50000, N=64, K=128; mfma_f32_16x16x32_bf16. In-place on d_out
//    (each block touches only its own 64 rows).
// ---------------------------------------------------------------------------
constexpr int A_STRIDE = 136;   // bf16 units; 272B row stride -> 2-way LDS conflict max

__global__ __launch_bounds__(256) void k_gemm(
    const float* __restrict__ x,
    const float* __restrict__ W_msg,  const float* __restrict__ b_msg,
    const float* __restrict__ W_self, const float* __restrict__ b_self,
    const unsigned* __restrict__ row_ptr,
    float* mean_and_out)            // d_out: read mean, write result (no restrict)
{
    __shared__ unsigned short A_sh[64 * A_STRIDE];
    __shared__ unsigned short B_sh[64 * A_STRIDE];
    __shared__ unsigned deg_sh[64];

    int tid = threadIdx.x;
    int r0 = blockIdx.x * 64;

    // stage A: rows r0..r0+63, k<64 from x, k>=64 from mean (both fp32 -> bf16)
    for (int idx = tid; idx < 64 * 32; idx += 256) {       // 32 float4-chunks per row
        int row = idx >> 5;
        int c4  = idx & 31;
        int grow = r0 + row;
        float4 v = make_float4(0.f, 0.f, 0.f, 0.f);
        int k;
        if (c4 < 16) { k = c4 * 4;        if (grow < N_NODES) v = *(const float4*)&x[grow * D + k]; }
        else         { k = (c4 - 16) * 4; if (grow < N_NODES) v = *(const float4*)&mean_and_out[grow * D + k];
                       k += 64; }
        unsigned* dst = (unsigned*)&A_sh[row * A_STRIDE + k];
        dst[0] = pack2(v.x, v.y);
        dst[1] = pack2(v.z, v.w);
    }
    // stage B: B_sh[n][k] ; k<64 = W_self[n][k], k>=64 = W_msg[n][k-64]
    for (int idx = tid; idx < 64 * 32; idx += 256) {
        int n  = idx >> 5;
        int c4 = idx & 31;
        float4 v;
        int k;
        if (c4 < 16) { k = c4 * 4;        v = *(const float4*)&W_self[n * D + k]; }
        else         { k = (c4 - 16) * 4; v = *(const float4*)&W_msg[n * D + k]; k += 64; }
        unsigned* dst = (unsigned*)&B_sh[n * A_STRIDE + k];
        dst[0] = pack2(v.x, v.y);
        dst[1] = pack2(v.z, v.w);
    }
    if (tid < 64) {
        int grow = r0 + tid;
        deg_sh[tid] = (grow < N_NODES) ? (row_ptr[grow + 1] - row_ptr[grow]) : 0u;
    }
    __syncthreads();

    int w    = tid >> 6;         // wave 0..3 -> rows 16w..16w+15
    int lane = tid & 63;
    int quad = lane >> 4;
    int l15  = lane & 15;

    f32x4 acc[4] = {{0.f,0.f,0.f,0.f},{0.f,0.f,0.f,0.f},{0.f,0.f,0.f,0.f},{0.f,0.f,0.f,0.f}};

    #pragma unroll
    for (int k0 = 0; k0 < 128; k0 += 32) {
        // A-frag: A[m=l15][k = k0 + quad*8 + j]
        short8 a = *(const short8*)&A_sh[(16 * w + l15) * A_STRIDE + k0 + quad * 8];
        #pragma unroll
        for (int nt = 0; nt < 4; ++nt) {
            short8 b = *(const short8*)&B_sh[(16 * nt + l15) * A_STRIDE + k0 + quad * 8];
            acc[nt] = __builtin_amdgcn_mfma_f32_16x16x32_bf16(a, b, acc[nt], 0, 0, 0);
        }
    }

    // D layout: col = lane&15, row = quad*4 + reg
    #pragma unroll
    for (int nt = 0; nt < 4; ++nt) {
        int col = nt * 16 + l15;
        float bs = b_self[col];
        float bm = b_msg[col];
        #pragma unroll
        for (int r = 0; r < 4; ++r) {
            int lrow = 16 * w + quad * 4 + r;
            int grow = r0 + lrow;
            if (grow < N_NODES) {
                float v = acc[nt][r] + bs + (deg_sh[lrow] > 0u ? bm : 0.0f);
                mean_and_out[grow * D + col] = v;
            }
        }
    }
}

// ---------------------------------------------------------------------------
extern "C" void kernel_launch(void* const* d_in, const int* in_sizes, int n_in,
                              void* d_out, int out_size, void* d_ws, size_t ws_size,
                              hipStream_t stream) {
    const float* x      = (const float*)d_in[0];
    const int*   edges  = (const int*)  d_in[1];
    const float* W_msg  = (const float*)d_in[2];
    const float* b_msg  = (const float*)d_in[3];
    const float* W_self = (const float*)d_in[4];
    const float* b_self = (const float*)d_in[5];
    float*       out    = (float*)d_out;

    // workspace layout (u32 units) — total ~3.8 MB
    unsigned* counts     = (unsigned*)d_ws;          // 50000
    unsigned* row_ptr    = counts + 51200;           // 50001
    unsigned* cursor     = counts + 102400;          // 50000
    unsigned* block_sums = counts + 153600;          // 256
    unsigned* edge_src   = counts + 154624;          // 800000

    hipMemsetAsync(counts, 0, (size_t)N_NODES * sizeof(unsigned), stream);

    int eb = (N_EDGES + 255) / 256;                  // 3125
    k_hist <<<eb, 256, 0, stream>>>(edges, counts);
    k_scan_a<<<SCAN_BLOCKS, 256, 0, stream>>>(counts, row_ptr, block_sums);
    k_scan_b<<<1, 256, 0, stream>>>(block_sums);
    k_scan_c<<<SCAN_BLOCKS, 256, 0, stream>>>(row_ptr, block_sums, cursor);
    k_place <<<eb, 256, 0, stream>>>(edges, cursor, edge_src);

    k_gather<<<(N_NODES + 3) / 4, 256, 0, stream>>>(x, row_ptr, edge_src, out);

    int gb = (N_NODES + 63) / 64;                    // 782
    k_gemm<<<gb, 256, 0, stream>>>(x, W_msg, b_msg, W_self, b_self, row_ptr, out);
}

// Round 4
// 209.089 us; speedup vs baseline: 1.8661x; 1.0176x over previous
//
#include <hip/hip_runtime.h>

constexpr int N_NODES = 50000;
constexpr int N_EDGES = 800000;
constexpr int D = 64;

constexpr int SCAN_BLOCKS = (N_NODES + 255) / 256;   // 196

typedef __attribute__((ext_vector_type(8))) short short8;
typedef __attribute__((ext_vector_type(4))) float f32x4;

static __device__ inline unsigned short f2bf(float f) {
    unsigned u = __float_as_uint(f);
    unsigned r = (u + 0x7FFFu + ((u >> 16) & 1u)) >> 16;   // RNE
    return (unsigned short)r;
}
static __device__ inline unsigned pack2(float lo, float hi) {
    return (unsigned)f2bf(lo) | ((unsigned)f2bf(hi) << 16);
}
static __device__ inline float bf2f(unsigned short b) {
    return __uint_as_float((unsigned)b << 16);
}

// ---------------------------------------------------------------------------
// 0) x (fp32) -> x_bf16, once. 4 elements per thread.
// ---------------------------------------------------------------------------
__global__ __launch_bounds__(256) void k_convert(
    const float* __restrict__ x, unsigned short* __restrict__ xb)
{
    int t = blockIdx.x * 256 + threadIdx.x;
    if (t < N_NODES * D / 4) {
        float4 v = ((const float4*)x)[t];
        uint2 p;
        p.x = pack2(v.x, v.y);
        p.y = pack2(v.z, v.w);
        ((uint2*)xb)[t] = p;
    }
}

// ---------------------------------------------------------------------------
// 1) histogram of destination degrees
// ---------------------------------------------------------------------------
__global__ __launch_bounds__(256) void k_hist(
    const int* __restrict__ edge_index, unsigned* __restrict__ counts)
{
    int t = blockIdx.x * 256 + threadIdx.x;
    if (t < N_EDGES) {
        int col = edge_index[N_EDGES + t];
        atomicAdd(&counts[col], 1u);
    }
}

// ---------------------------------------------------------------------------
// 2) exclusive scan of counts -> row_ptr (3 kernels)
// ---------------------------------------------------------------------------
__global__ __launch_bounds__(256) void k_scan_a(
    const unsigned* __restrict__ counts,
    unsigned* __restrict__ row_ptr, unsigned* __restrict__ block_sums)
{
    __shared__ unsigned s[256];
    int t = threadIdx.x;
    int i = blockIdx.x * 256 + t;
    unsigned c = (i < N_NODES) ? counts[i] : 0u;
    s[t] = c;
    __syncthreads();
    for (int off = 1; off < 256; off <<= 1) {
        unsigned v = (t >= off) ? s[t - off] : 0u;
        __syncthreads();
        s[t] += v;
        __syncthreads();
    }
    if (i < N_NODES) row_ptr[i] = s[t] - c;
    if (t == 255) block_sums[blockIdx.x] = s[255];
}

__global__ __launch_bounds__(256) void k_scan_b(unsigned* __restrict__ block_sums)
{
    __shared__ unsigned s[256];
    int t = threadIdx.x;
    unsigned c = (t < SCAN_BLOCKS) ? block_sums[t] : 0u;
    s[t] = c;
    __syncthreads();
    for (int off = 1; off < 256; off <<= 1) {
        unsigned v = (t >= off) ? s[t - off] : 0u;
        __syncthreads();
        s[t] += v;
        __syncthreads();
    }
    if (t < SCAN_BLOCKS) block_sums[t] = s[t] - c;
}

__global__ __launch_bounds__(256) void k_scan_c(
    unsigned* __restrict__ row_ptr, const unsigned* __restrict__ block_sums,
    unsigned* __restrict__ cursor)
{
    int i = blockIdx.x * 256 + threadIdx.x;
    if (i < N_NODES) {
        unsigned v = row_ptr[i] + block_sums[blockIdx.x];
        row_ptr[i] = v;
        cursor[i] = v;
    }
    if (i == 0) row_ptr[N_NODES] = (unsigned)N_EDGES;
}

// ---------------------------------------------------------------------------
// 3) placement: CSR adjacency, sources stored as u16 (src < 65536)
// ---------------------------------------------------------------------------
__global__ __launch_bounds__(256) void k_place(
    const int* __restrict__ edge_index,
    unsigned* __restrict__ cursor, unsigned short* __restrict__ edge_src)
{
    int t = blockIdx.x * 256 + threadIdx.x;
    if (t < N_EDGES) {
        int r = edge_index[t];
        int c = edge_index[N_EDGES + t];
        unsigned p = atomicAdd(&cursor[c], 1u);
        edge_src[p] = (unsigned short)r;
    }
}

// ---------------------------------------------------------------------------
// 4) fused gather-mean + GEMM.
//    Block = 256 threads (4 waves) = 64 nodes.
//    Phase A: stage this block's x_bf16 rows into A_sh[k<64], W into B_sh.
//    Phase B: each wave gathers means for its 16 nodes (quarter-wave per
//             edge, 4 edge-rows in flight), writes bf16 mean into A_sh[k>=64].
//    Phase C: verified 16x16x32 bf16 MFMA, out = A @ B^T + biases.
// ---------------------------------------------------------------------------
constexpr int A_STRIDE = 136;   // u16 units; 272B row stride (16B-aligned rows)

__global__ __launch_bounds__(256) void k_fused(
    const unsigned short* __restrict__ x_bf16,
    const float* __restrict__ W_msg,  const float* __restrict__ b_msg,
    const float* __restrict__ W_self, const float* __restrict__ b_self,
    const unsigned* __restrict__ row_ptr,
    const unsigned short* __restrict__ edge_src,
    float* __restrict__ out)
{
    __shared__ __align__(16) unsigned short A_sh[64 * A_STRIDE];
    __shared__ __align__(16) unsigned short B_sh[64 * A_STRIDE];
    __shared__ unsigned deg_sh[64];

    int tid = threadIdx.x;
    int r0 = blockIdx.x * 64;

    // --- Phase A: stage x rows. chunk c = elements 4c..4c+3 (uint2 = 4 u16).
    for (int idx = tid; idx < 64 * 16; idx += 256) {
        int row = idx >> 4;
        int c   = idx & 15;
        int g   = r0 + row;
        uint2 v = make_uint2(0u, 0u);
        if (g < N_NODES) v = *(const uint2*)&x_bf16[g * D + c * 4];
        *(uint2*)&A_sh[row * A_STRIDE + c * 4] = v;
    }
    // stage B: k<64 = W_self, k>=64 = W_msg (fp32 -> bf16)
    for (int idx = tid; idx < 64 * 32; idx += 256) {
        int n  = idx >> 5;
        int c4 = idx & 31;
        float4 v;
        int k;
        if (c4 < 16) { k = c4 * 4;        v = *(const float4*)&W_self[n * D + k]; }
        else         { k = (c4 - 16) * 4; v = *(const float4*)&W_msg[n * D + k]; k += 64; }
        unsigned* dst = (unsigned*)&B_sh[n * A_STRIDE + k];
        dst[0] = pack2(v.x, v.y);
        dst[1] = pack2(v.z, v.w);
    }

    // --- Phase B: gather means. wave w -> rows 16w..16w+15.
    int w    = tid >> 6;
    int lane = tid & 63;
    int Q    = lane >> 4;      // quarter 0..3 -> which edge in the group of 4
    int f    = lane & 15;      // feature group: features 4f..4f+3

    for (int i = 0; i < 16; ++i) {
        int lrow = w * 16 + i;
        int node = r0 + lrow;
        unsigned start = 0, end = 0;
        if (node < N_NODES) { start = row_ptr[node]; end = row_ptr[node + 1]; }

        float a0 = 0.f, a1 = 0.f, a2 = 0.f, a3 = 0.f;
        for (unsigned base = start; base < end; base += 64u) {
            int m = (int)min(64u, end - base);
            int id = (lane < m) ? (int)edge_src[base + lane] : 0;
            for (int j = 0; j < m; j += 4) {
                int e = j + Q;
                int s = __shfl(id, e);
                if (e < m) {
                    ushort4 raw = *(const ushort4*)&x_bf16[s * D + 4 * f];
                    a0 += bf2f(raw.x);
                    a1 += bf2f(raw.y);
                    a2 += bf2f(raw.z);
                    a3 += bf2f(raw.w);
                }
            }
        }
        // reduce across the 4 quarters (lanes f, f+16, f+32, f+48)
        a0 += __shfl_xor(a0, 16); a1 += __shfl_xor(a1, 16);
        a2 += __shfl_xor(a2, 16); a3 += __shfl_xor(a3, 16);
        a0 += __shfl_xor(a0, 32); a1 += __shfl_xor(a1, 32);
        a2 += __shfl_xor(a2, 32); a3 += __shfl_xor(a3, 32);

        unsigned deg = end - start;
        float inv = deg ? 1.0f / (float)deg : 0.0f;
        if (Q == 0) {
            uint2 p;
            p.x = pack2(a0 * inv, a1 * inv);
            p.y = pack2(a2 * inv, a3 * inv);
            *(uint2*)&A_sh[lrow * A_STRIDE + 64 + 4 * f] = p;
            if (f == 0) deg_sh[lrow] = deg;
        }
    }
    __syncthreads();

    // --- Phase C: MFMA (layout verified in round 2)
    int quad = lane >> 4;
    int l15  = lane & 15;

    f32x4 acc[4] = {{0.f,0.f,0.f,0.f},{0.f,0.f,0.f,0.f},{0.f,0.f,0.f,0.f},{0.f,0.f,0.f,0.f}};

    #pragma unroll
    for (int k0 = 0; k0 < 128; k0 += 32) {
        short8 a = *(const short8*)&A_sh[(16 * w + l15) * A_STRIDE + k0 + quad * 8];
        #pragma unroll
        for (int nt = 0; nt < 4; ++nt) {
            short8 b = *(const short8*)&B_sh[(16 * nt + l15) * A_STRIDE + k0 + quad * 8];
            acc[nt] = __builtin_amdgcn_mfma_f32_16x16x32_bf16(a, b, acc[nt], 0, 0, 0);
        }
    }

    #pragma unroll
    for (int nt = 0; nt < 4; ++nt) {
        int col = nt * 16 + l15;
        float bs = b_self[col];
        float bm = b_msg[col];
        #pragma unroll
        for (int r = 0; r < 4; ++r) {
            int lrow = 16 * w + quad * 4 + r;
            int grow = r0 + lrow;
            if (grow < N_NODES) {
                float v = acc[nt][r] + bs + (deg_sh[lrow] > 0u ? bm : 0.0f);
                out[grow * D + col] = v;
            }
        }
    }
}

// ---------------------------------------------------------------------------
extern "C" void kernel_launch(void* const* d_in, const int* in_sizes, int n_in,
                              void* d_out, int out_size, void* d_ws, size_t ws_size,
                              hipStream_t stream) {
    const float* x      = (const float*)d_in[0];
    const int*   edges  = (const int*)  d_in[1];
    const float* W_msg  = (const float*)d_in[2];
    const float* b_msg  = (const float*)d_in[3];
    const float* W_self = (const float*)d_in[4];
    const float* b_self = (const float*)d_in[5];
    float*       out    = (float*)d_out;

    // workspace layout (bytes) — total ~8.6 MB
    char* ws = (char*)d_ws;
    unsigned*       counts     = (unsigned*)(ws + 0);          // 200000 B
    unsigned*       row_ptr    = (unsigned*)(ws + 204800);     // 200004 B
    unsigned*       cursor     = (unsigned*)(ws + 409600);     // 200000 B
    unsigned*       block_sums = (unsigned*)(ws + 614400);     // 1024 B
    unsigned short* edge_src   = (unsigned short*)(ws + 616448);  // 1.6 MB
    unsigned short* x_bf16     = (unsigned short*)(ws + 2240000); // 6.4 MB

    hipMemsetAsync(counts, 0, (size_t)N_NODES * sizeof(unsigned), stream);

    int eb = (N_EDGES + 255) / 256;                  // 3125
    k_convert<<<(N_NODES * D / 4 + 255) / 256, 256, 0, stream>>>(x, x_bf16);
    k_hist <<<eb, 256, 0, stream>>>(edges, counts);
    k_scan_a<<<SCAN_BLOCKS, 256, 0, stream>>>(counts, row_ptr, block_sums);
    k_scan_b<<<1, 256, 0, stream>>>(block_sums);
    k_scan_c<<<SCAN_BLOCKS, 256, 0, stream>>>(row_ptr, block_sums, cursor);
    k_place <<<eb, 256, 0, stream>>>(edges, cursor, edge_src);

    int gb = (N_NODES + 63) / 64;                    // 782
    k_fused<<<gb, 256, 0, stream>>>(x_bf16, W_msg, b_msg, W_self, b_self,
                                    row_ptr, edge_src, out);
}